// Round 17
// baseline (109.378 us; speedup 1.0000x reference)
//
#include <hip/hip_runtime.h>
#include <hip/hip_bf16.h>

#define NSPK 1024
#define MU 32
#define DIM 512
#define DIMP (DIM + 8)
#define NROW (NSPK * MU)   // 32768
#define EPS 1e-6f

typedef __attribute__((ext_vector_type(16))) float f32x16;
typedef __attribute__((ext_vector_type(8))) short bf16x8;

#define GLOAD_LDS16(g, l)                                          \
  __builtin_amdgcn_global_load_lds(                                \
      (const __attribute__((address_space(1))) void*)(g),          \
      (__attribute__((address_space(3))) void*)(l), 16, 0, 0)

__device__ inline ushort f2bf(float x) {
  __hip_bfloat16 h = __float2bfloat16(x);
  return *reinterpret_cast<ushort*>(&h);
}

// ---------------------------------------------------------------------------
// Kernel 1: per-speaker prep. LOO cosines (fp32 exact) + normalized bf16
// A and B in 32-WIDE MFMA-FRAGMENT-MAJOR layout for mfma_32x32x16_bf16:
//   frag(rb32, kf16) = 512 ushorts; lane l holds row/col = base32 + (l&31),
//   k = kf*16 + (l>>5)*8 .. +8 (16 B chunk). Speaker j == A-frag-row j.
// grid = NSPK, block = 256
// ---------------------------------------------------------------------------
__global__ __launch_bounds__(256) void k_prep(
    const float* __restrict__ dvecs,
    ushort* __restrict__ Af,    // [1024 rb32][32 kf][64 lane][8]
    ushort* __restrict__ Bf,    // [32 nb32][32 kf][64 lane][8]
    float* __restrict__ loo)    // [NROW]
{
  const int j = blockIdx.x, t = threadIdx.x;
  __shared__ float sD[MU * DIMP];   // padded raw speaker rows (66.5 KiB)
  __shared__ float sS[DIM];
  __shared__ float sred[4];
  __shared__ float sS2v;
  __shared__ float sInv[MU];

  const float* base = dvecs + (size_t)j * (MU * DIM);

  // single global read: stage rows + column sums
  float s0 = 0.f, s1 = 0.f;
  for (int m = 0; m < MU; ++m) {
    float a = base[m * DIM + t];
    float b = base[m * DIM + t + 256];
    sD[m * DIMP + t] = a;
    sD[m * DIMP + t + 256] = b;
    s0 += a; s1 += b;
  }
  sS[t] = s0; sS[t + 256] = s1;
  __syncthreads();

  // |S|^2
  float p = s0 * s0 + s1 * s1;
  for (int off = 32; off; off >>= 1) p += __shfl_down(p, off);
  if ((t & 63) == 0) sred[t >> 6] = p;
  __syncthreads();
  if (t == 0) sS2v = sred[0] + sred[1] + sred[2] + sred[3];
  __syncthreads();
  const float S2 = sS2v;

  // per-utterance dot(e,S), |e|^2 from LDS (8 lanes per row)
  const int g = t >> 3, l = t & 7;
  float dotS = 0.f, e2 = 0.f;
  for (int i = 0; i < DIM / 8; ++i) {
    int d = i * 8 + l;
    float ev = sD[g * DIMP + d];
    dotS += ev * sS[d];
    e2 += ev * ev;
  }
  for (int off = 4; off; off >>= 1) {
    dotS += __shfl_down(dotS, off);
    e2 += __shfl_down(e2, off);
  }
  if (l == 0) {
    float numer = dotS - e2;                          // e.(S-e)
    float d2 = fmaxf(S2 - 2.f * dotS + e2, 1e-30f);   // |S-e|^2
    loo[j * MU + g] = numer / (sqrtf(e2) * sqrtf(d2));
    sInv[g] = 1.f / sqrtf(e2);
  }
  __syncthreads();

  // A fragments: speaker j = rows j*32..+31 = frag-row j; 32 kf chunks.
  for (int i = 0; i < 8; ++i) {
    int idx = i * 256 + t;          // 0..2047 16B-chunks
    int kfg = idx >> 6;             // 0..31
    int lane2 = idx & 63;
    int m = lane2 & 31;
    int k0 = kfg * 16 + (lane2 >> 5) * 8;
    float inv = sInv[m];
    ushort tmp[8];
#pragma unroll
    for (int z = 0; z < 8; ++z) tmp[z] = f2bf(sD[m * DIMP + k0 + z] * inv);
    *(bf16x8*)&Af[(((size_t)j * 32 + kfg) << 9) + lane2 * 8] = *(bf16x8*)tmp;
  }

  // B fragment pieces for centroid j: col-lane = j&31 in frag-col j>>5.
  if (t < 64) {
    int kf = t >> 1, half = t & 1;
    int lane2 = half * 32 + (j & 31);
    float invc = 1.f / sqrtf(S2);
    int k0 = kf * 16 + half * 8;
    ushort tmp[8];
#pragma unroll
    for (int z = 0; z < 8; ++z) tmp[z] = f2bf(sS[k0 + z] * invc);
    *(bf16x8*)&Bf[(((size_t)(j >> 5) * 32 + kf) << 9) + lane2 * 8] =
        *(bf16x8*)tmp;
  }
}

// ---------------------------------------------------------------------------
// Kernel 2: 32x32-MFMA tiled GEMM, 3-buffer counted-vmcnt schedule (R12's).
// Block 128x256, BK=32 (16 K-steps), 256 thr (4 waves, 2wm x 2wn).
// Wave tile 64x128 = 2 rf x 4 cf of 32x32 frags: acc[2][4] f32x16 =
// 128 AGPR + ~90 arch (frag regs halve vs 16x16 at this tile -> avoids
// R14's 264-reg 1-wave/SIMD trap).
// R15 post-mortem: the ~50us plateau is LDS BANDWIDTH (6 MB/CU through
// one shared unit ~= 25-30us) -- geometry, not schedule. This tile cuts
// LDS to 4.5 MB/CU (12 KB reads per 524k FLOP/wave-step) and amortizes
// per-step sync over 2x FLOP; 32x32 MFMA adds ~20% matrix rate.
// Staging 6 loads/thread/step -> vmcnt(6) consume-wait, 2-deep prologue,
// lgkmcnt(0)+sched_barrier at step end (rule #18).
// LDS 3x24 KiB + 1 = 73 KiB -> 2 blocks/CU.
// Grid 1024 = 256 rb x 4 cb, XCD-chunked swizzle (32-rb band per XCD).
// ---------------------------------------------------------------------------
__global__ __launch_bounds__(256, 1) void k_gemm(
    const ushort* __restrict__ Af,
    const ushort* __restrict__ Bf,
    const float* __restrict__ wp,
    float* __restrict__ part,    // [4][NROW] partial sumexp per col-chunk
    float* __restrict__ diag)    // [NROW] raw cos vs own full centroid
{
  __shared__ ushort ldsA[3 * 8 * 512];    // 24 KiB: 3 bufs x 8 frags
  __shared__ ushort ldsB[3 * 16 * 512];   // 48 KiB: 3 bufs x 16 frags
  __shared__ float sPart[128][2];         // 1 KiB

  const int t = threadIdx.x;
  const int w = t >> 6, lane = t & 63;
  const int hi = lane >> 5;               // k-half / row-half selector
  const int wm = w >> 1, wn = w & 1;      // 2 x 2 wave grid
  // XCD-chunked block swizzle
  const int bid = blockIdx.x;
  const int xcd = bid & 7, ii = bid >> 3;     // ii in [0,128) per XCD
  const int rb = xcd * 32 + (ii >> 2);        // 0..255 (128 rows each)
  const int cb = ii & 3;                      // 0..3   (256 cols each)

  f32x16 acc[2][4];
#pragma unroll
  for (int a = 0; a < 2; ++a)
#pragma unroll
    for (int b = 0; b < 4; ++b) acc[a][b] = (f32x16)0.f;

  // staging: 8 A-frags (4 rf32 x 2 kh) + 16 B-frags (8 cf32 x 2 kh) per
  // step; wave w stages rf32=w (2 loads) and cf32={w, w+4} (4 loads).
  const ushort* gA  = Af + (((size_t)(rb * 4 + w) * 32) << 9) + lane * 8;
  const ushort* gB0 = Bf + (((size_t)(cb * 8 + w) * 32) << 9) + lane * 8;
  const ushort* gB1 = Bf + (((size_t)(cb * 8 + w + 4) * 32) << 9) + lane * 8;
  ushort* dA0 = &ldsA[(w * 2) * 512 + lane * 8];
  ushort* dA1 = &ldsA[(w * 2 + 1) * 512 + lane * 8];
  ushort* dB0 = &ldsB[(w * 2) * 512 + lane * 8];
  ushort* dB1 = &ldsB[(w * 2 + 1) * 512 + lane * 8];
  ushort* dB2 = &ldsB[((w + 4) * 2) * 512 + lane * 8];
  ushort* dB3 = &ldsB[((w + 4) * 2 + 1) * 512 + lane * 8];

#define STAGE(kt, bi)                                       \
  {                                                         \
    GLOAD_LDS16(gA + (2 * (kt)) * 512, dA0 + (bi) * 4096);  \
    GLOAD_LDS16(gA + (2 * (kt) + 1) * 512, dA1 + (bi) * 4096); \
    GLOAD_LDS16(gB0 + (2 * (kt)) * 512, dB0 + (bi) * 8192); \
    GLOAD_LDS16(gB0 + (2 * (kt) + 1) * 512, dB1 + (bi) * 8192); \
    GLOAD_LDS16(gB1 + (2 * (kt)) * 512, dB2 + (bi) * 8192); \
    GLOAD_LDS16(gB1 + (2 * (kt) + 1) * 512, dB3 + (bi) * 8192); \
  }

  // fragment read bases: A frag (wm*2+rf)*2+kh ; B frag (wn*4+cf)*2+kh
  const ushort* lA0 = &ldsA[(wm * 2) * 1024 + lane * 8];
  const ushort* lB0 = &ldsB[(wn * 4) * 1024 + lane * 8];

  // ---- prologue: 2-deep stage prefetch (12 loads/thread in flight) ----
  STAGE(0, 0);
  STAGE(1, 1);

  // ---- pipelined K-loop ----
#pragma unroll
  for (int kt = 0; kt < 16; ++kt) {
    if (kt < 15) {
      asm volatile("s_waitcnt vmcnt(6)" ::: "memory");  // stage(kt) landed
    } else {
      asm volatile("s_waitcnt vmcnt(0)" ::: "memory");
    }
    __builtin_amdgcn_s_barrier();
    __builtin_amdgcn_sched_barrier(0);

    if (kt <= 13) STAGE(kt + 2, (kt + 2) % 3);

    const ushort* lA = lA0 + (kt % 3) * 4096;
    const ushort* lB = lB0 + (kt % 3) * 8192;
#pragma unroll
    for (int kh = 0; kh < 2; ++kh) {
      bf16x8 afr[2], bfr[4];
#pragma unroll
      for (int cf = 0; cf < 4; ++cf)
        bfr[cf] = *(const bf16x8*)(lB + (cf * 2 + kh) * 512);
#pragma unroll
      for (int rf = 0; rf < 2; ++rf)
        afr[rf] = *(const bf16x8*)(lA + (rf * 2 + kh) * 512);

      __builtin_amdgcn_s_setprio(1);
#pragma unroll
      for (int rf = 0; rf < 2; ++rf)
#pragma unroll
        for (int cf = 0; cf < 4; ++cf)
          acc[rf][cf] = __builtin_amdgcn_mfma_f32_32x32x16_bf16(
              afr[rf], bfr[cf], acc[rf][cf], 0, 0, 0);
      __builtin_amdgcn_s_setprio(0);
    }

    if (kt < 15) {
      asm volatile("s_waitcnt lgkmcnt(0)" ::: "memory");  // buf safety
      __builtin_amdgcn_sched_barrier(0);
    }
  }
#undef STAGE

  const float W = *wp;

  // ---- diag capture (raw cos) before exp consumes acc ----
  // C/D layout (32x32): col = lane&31, row = (i&3)+8*(i>>2)+4*hi.
  // Block speakers sp=0..3: col c = rb*4+sp, in block iff cb == c>>8;
  // rows of sp live in rf32 = sp -> wave wm = sp>>1, rf = sp&1.
  if (cb == (rb >> 6)) {
#pragma unroll
    for (int sp = 0; sp < 4; ++sp) {
      const int c = rb * 4 + sp;
      if (wm == (sp >> 1) && wn == ((c >> 7) & 1)) {
        const int nfo = (c >> 5) & 3;
        f32x16 dsel = acc[sp & 1][0];
#pragma unroll
        for (int cf = 1; cf < 4; ++cf)
          if (cf == nfo) dsel = acc[sp & 1][cf];   // static idx only
        if ((lane & 31) == (c & 31)) {
#pragma unroll
          for (int i = 0; i < 16; ++i)
            diag[c * 32 + (i & 3) + 8 * (i >> 2) + 4 * hi] = dsel[i];
        }
      }
    }
  }

  // ---- fused epilogue: exp((fmax(cos,eps)-1)*W), reduce over 128 cols ----
#pragma unroll
  for (int rf = 0; rf < 2; ++rf)
#pragma unroll
    for (int i = 0; i < 16; ++i) {
      float s = 0.f;
#pragma unroll
      for (int cf = 0; cf < 4; ++cf)
        s += __expf((fmaxf(acc[rf][cf][i], EPS) - 1.f) * W);
      // reduce over the 32 cols (lanes within each 32-lane half)
      s += __shfl_xor(s, 1);
      s += __shfl_xor(s, 2);
      s += __shfl_xor(s, 4);
      s += __shfl_xor(s, 8);
      s += __shfl_xor(s, 16);
      if ((lane & 31) == 0)
        sPart[wm * 64 + rf * 32 + (i & 3) + 8 * (i >> 2) + 4 * hi][wn] = s;
    }
  __syncthreads();
  if (t < 128)
    part[(size_t)cb * NROW + rb * 128 + t] = sPart[t][0] + sPart[t][1];
}

// ---------------------------------------------------------------------------
// Final: sum 4 col-chunk partials, swap exp(diag)->exp(loo), close lse,
// deterministic 2-stage sum.  L_row = log(s - exp(dt) + exp(lt)) - lt
// ---------------------------------------------------------------------------
__global__ __launch_bounds__(256) void k_final1(
    const float* __restrict__ part, const float* __restrict__ loo,
    const float* __restrict__ diag, const float* __restrict__ wp,
    float* __restrict__ p2)
{
  const int t = threadIdx.x;
  const int r = blockIdx.x * 256 + t;
  const float W = *wp;
  float s = 0.f;
#pragma unroll
  for (int c = 0; c < 4; ++c) s += part[(size_t)c * NROW + r];
  const float lt = (fmaxf(loo[r], EPS) - 1.f) * W;
  const float dt = (fmaxf(diag[r], EPS) - 1.f) * W;
  s += __expf(lt) - __expf(dt);
  float v = logf(s) - lt;
  __shared__ float red[4];
  for (int off = 32; off; off >>= 1) v += __shfl_down(v, off);
  if ((t & 63) == 0) red[t >> 6] = v;
  __syncthreads();
  if (t == 0) p2[blockIdx.x] = red[0] + red[1] + red[2] + red[3];
}

__global__ __launch_bounds__(128) void k_final2(
    const float* __restrict__ p2, float* __restrict__ out)
{
  const int t = threadIdx.x;
  float v = p2[t];
  for (int off = 32; off; off >>= 1) v += __shfl_down(v, off);
  __shared__ float red[2];
  if ((t & 63) == 0) red[t >> 6] = v;
  __syncthreads();
  if (t == 0) out[0] = red[0] + red[1];
}

extern "C" void kernel_launch(void* const* d_in, const int* in_sizes, int n_in,
                              void* d_out, int out_size, void* d_ws, size_t ws_size,
                              hipStream_t stream) {
  const float* dvecs = (const float*)d_in[0];
  const float* wptr  = (const float*)d_in[1];
  // b cancels algebraically (shift = w+b subtracted and re-added) -> unused
  float* out = (float*)d_out;

  char* ws = (char*)d_ws;
  ushort* Af = (ushort*)ws;  ws += (size_t)NROW * DIM * sizeof(ushort); // 32 MiB
  ushort* Bf = (ushort*)ws;  ws += (size_t)NSPK * DIM * sizeof(ushort); // 1 MiB
  float* loo  = (float*)ws;  ws += (size_t)NROW * sizeof(float);
  float* diag = (float*)ws;  ws += (size_t)NROW * sizeof(float);
  float* part = (float*)ws;  ws += (size_t)4 * NROW * sizeof(float);    // 512 KiB
  float* p2   = (float*)ws;

  k_prep<<<NSPK, 256, 0, stream>>>(dvecs, Af, Bf, loo);
  k_gemm<<<1024, 256, 0, stream>>>(Af, Bf, wptr, part, diag);
  k_final1<<<NROW / 256, 256, 0, stream>>>(part, loo, diag, wptr, p2);
  k_final2<<<1, 128, 0, stream>>>(p2, out);
}

// Round 18
// 66.194 us; speedup vs baseline: 1.6524x; 1.6524x over previous
//
#include <hip/hip_runtime.h>
#include <hip/hip_bf16.h>

#define NSPK 1024
#define MU 32
#define DIM 512
#define DIMP (DIM + 8)
#define NROW (NSPK * MU)   // 32768
#define EPS 1e-6f

typedef __attribute__((ext_vector_type(4))) float f32x4;
typedef __attribute__((ext_vector_type(2))) long i64x2;

#define GLOAD_LDS16(g, l)                                          \
  __builtin_amdgcn_global_load_lds(                                \
      (const __attribute__((address_space(1))) void*)(g),          \
      (__attribute__((address_space(3))) void*)(l), 16, 0, 0)

// ---------------------------------------------------------------------------
// Kernel 1: per-speaker prep. LOO cosines (fp32 exact) + normalized FP8-e4m3
// A and B blobs in step-major, pair-packed fragment layout:
//   A: [rb128][kt 16][rp 4][lane 64][pair 2][8B]  (64 KiB per 128-row block)
//   frag f = 2*rp+pair holds rows f*16..f*16+15; lane l: row = l&15,
//   k = kt*32 + (l>>4)*8 + z, byte = rp*1024 + l*16 + pair*8 + z.
//   B identical with cols. One b128 LDS read = 2 frags (a pair).
// grid = NSPK, block = 256
// ---------------------------------------------------------------------------
__global__ __launch_bounds__(256) void k_prep(
    const float* __restrict__ dvecs,
    char* __restrict__ Af8,     // [256][65536] bytes = 16 MiB
    char* __restrict__ Bf8,     // [8][65536] bytes = 512 KiB
    float* __restrict__ loo)    // [NROW]
{
  const int j = blockIdx.x, t = threadIdx.x;
  __shared__ float sD[MU * DIMP];   // padded raw speaker rows (66.5 KiB)
  __shared__ float sS[DIM];
  __shared__ float sred[4];
  __shared__ float sS2v;
  __shared__ float sInv[MU];

  const float* base = dvecs + (size_t)j * (MU * DIM);

  // single global read: stage rows + column sums
  float s0 = 0.f, s1 = 0.f;
  for (int m = 0; m < MU; ++m) {
    float a = base[m * DIM + t];
    float b = base[m * DIM + t + 256];
    sD[m * DIMP + t] = a;
    sD[m * DIMP + t + 256] = b;
    s0 += a; s1 += b;
  }
  sS[t] = s0; sS[t + 256] = s1;
  __syncthreads();

  // |S|^2
  float p = s0 * s0 + s1 * s1;
  for (int off = 32; off; off >>= 1) p += __shfl_down(p, off);
  if ((t & 63) == 0) sred[t >> 6] = p;
  __syncthreads();
  if (t == 0) sS2v = sred[0] + sred[1] + sred[2] + sred[3];
  __syncthreads();
  const float S2 = sS2v;

  // per-utterance dot(e,S), |e|^2 from LDS (8 lanes per row)
  const int g = t >> 3, l = t & 7;
  float dotS = 0.f, e2 = 0.f;
  for (int i = 0; i < DIM / 8; ++i) {
    int d = i * 8 + l;
    float ev = sD[g * DIMP + d];
    dotS += ev * sS[d];
    e2 += ev * ev;
  }
  for (int off = 4; off; off >>= 1) {
    dotS += __shfl_down(dotS, off);
    e2 += __shfl_down(e2, off);
  }
  if (l == 0) {
    float numer = dotS - e2;                          // e.(S-e)
    float d2 = fmaxf(S2 - 2.f * dotS + e2, 1e-30f);   // |S-e|^2
    loo[j * MU + g] = numer / (sqrtf(e2) * sqrtf(d2));
    sInv[g] = 1.f / sqrtf(e2);
  }
  __syncthreads();

  // A fp8 blob: speaker j = rows (j&3)*32..+31 of rb128 = j>>2.
  // rp = j&3 (constant), pair = (m>>4)&1, lane = lk*16 + (m&15).
  for (int i = 0; i < 8; ++i) {
    int idx = i * 256 + t;        // 0..2047
    int m = idx >> 6;             // utterance 0..31
    int c = idx & 63;             // 8-elem k-chunk
    int kt = c >> 2, lk = c & 3;
    float inv = sInv[m];
    const float* src = &sD[m * DIMP + c * 8];
    int b0 = 0, b1 = 0;
    b0 = __builtin_amdgcn_cvt_pk_fp8_f32(src[0] * inv, src[1] * inv, b0, false);
    b0 = __builtin_amdgcn_cvt_pk_fp8_f32(src[2] * inv, src[3] * inv, b0, true);
    b1 = __builtin_amdgcn_cvt_pk_fp8_f32(src[4] * inv, src[5] * inv, b1, false);
    b1 = __builtin_amdgcn_cvt_pk_fp8_f32(src[6] * inv, src[7] * inv, b1, true);
    size_t byte = ((size_t)(j >> 2) << 16) + ((size_t)kt << 12) +
                  ((size_t)(j & 3) << 10) + (lk * 16 + (m & 15)) * 16 +
                  (((m >> 4) & 1) << 3);
    *(int2*)(Af8 + byte) = make_int2(b0, b1);
  }

  // B fp8 blob: centroid j -> nb128 = j>>7, cp = (j>>5)&3, pair = (j>>4)&1,
  // lane = lk*16 + (j&15).
  if (t < 64) {
    int c = t;                    // k-chunk 0..63
    int kt = c >> 2, lk = c & 3;
    float invc = 1.f / sqrtf(S2);
    const float* src = &sS[c * 8];
    int b0 = 0, b1 = 0;
    b0 = __builtin_amdgcn_cvt_pk_fp8_f32(src[0] * invc, src[1] * invc, b0, false);
    b0 = __builtin_amdgcn_cvt_pk_fp8_f32(src[2] * invc, src[3] * invc, b0, true);
    b1 = __builtin_amdgcn_cvt_pk_fp8_f32(src[4] * invc, src[5] * invc, b1, false);
    b1 = __builtin_amdgcn_cvt_pk_fp8_f32(src[6] * invc, src[7] * invc, b1, true);
    size_t byte = ((size_t)(j >> 7) << 16) + ((size_t)kt << 12) +
                  ((size_t)((j >> 5) & 3) << 10) + (lk * 16 + (j & 15)) * 16 +
                  (((j >> 4) & 1) << 3);
    *(int2*)(Bf8 + byte) = make_int2(b0, b1);
  }
}

// ---------------------------------------------------------------------------
// Kernel 2: FP8 MFMA tiled GEMM, 4-buffer counted-vmcnt pipeline.
// Tile 128x128, BK=32 (16 K-steps), 256 thr (4 waves, 2wm x 2wn), wave
// tile 64x64 (acc[4][4] = 64 regs -- the only acc size that keeps
// >=2 waves/SIMD; R14/R16/R17 all hit the 256-reg unified wall).
// fp8 halves every byte pipe vs R13: LDS 6->3 MB/CU, L2 512->256 MB,
// stage = 2 loads/thread/step (4 KB tile), ds_read = 4 b128/wave/step
// (pair-packed frags). MFMA (16.6us/CU) is now the dominant pipe.
// Schedule: counted vmcnt(2) consume-wait (stage(kt+1) landed, kt+2
// flying), raw s_barrier, STAGE(kt+3) into buf[(kt+3)&3] (writer 2 iters
// behind reader -> rigorously safe), DSREAD(kt+1) no-wait (overlaps MFMA
// via register double-buffer), counted lgkmcnt(4) (only 1-iter-old reads
// drained). All waits are on >=1-iter-old ops = free.
// LDS 2x16 KiB + 1 = 33 KiB; VGPR ~110 + 64 acc -> 2-3 waves/SIMD.
// Grid 2048 = 256 rb x 8 cb, XCD-chunked swizzle (32-rb band per XCD).
// ---------------------------------------------------------------------------
__global__ __launch_bounds__(256, 1) void k_gemm(
    const char* __restrict__ Af8,
    const char* __restrict__ Bf8,
    const float* __restrict__ wp,
    float* __restrict__ part,    // [8][NROW] partial sumexp per col-chunk
    float* __restrict__ diag)    // [NROW] raw cos vs own full centroid
{
  __shared__ char ldsA[4 * 4096];   // 16 KiB: 4 bufs x 4 KiB step-tile
  __shared__ char ldsB[4 * 4096];   // 16 KiB
  __shared__ float sPart[128][2];   // 1 KiB

  const int t = threadIdx.x;
  const int w = t >> 6, lane = t & 63;
  const int lr = lane & 15, lk = lane >> 4;
  const int wm = w >> 1, wn = w & 1;      // 2 x 2 wave grid
  // XCD-chunked block swizzle
  const int bid = blockIdx.x;
  const int xcd = bid & 7, ii = bid >> 3;     // ii in [0,256) per XCD
  const int rb = xcd * 32 + (ii >> 3);        // 0..255 (128 rows each)
  const int cb = ii & 7;                      // 0..7   (128 cols each)

  f32x4 acc[4][4];
#pragma unroll
  for (int a = 0; a < 4; ++a)
#pragma unroll
    for (int b = 0; b < 4; ++b) acc[a][b] = (f32x4)0.f;

  // staging: one 16B chunk per thread per tile (A and B)
  const char* gA = Af8 + ((size_t)rb << 16) + t * 16;
  const char* gB = Bf8 + ((size_t)cb << 16) + t * 16;
  char* dA = &ldsA[t * 16];
  char* dB = &ldsB[t * 16];

#define STAGE(kt, bi)                                     \
  {                                                       \
    GLOAD_LDS16(gA + ((size_t)(kt) << 12), dA + ((bi) << 12)); \
    GLOAD_LDS16(gB + ((size_t)(kt) << 12), dB + ((bi) << 12)); \
  }

  // fragment register double-buffer: each b128 = 2 fp8 frags (a pair)
  i64x2 aP[2][2], bP[2][2];
  const char* lA0 = &ldsA[(wm * 2) * 1024 + lane * 16];
  const char* lB0 = &ldsB[(wn * 2) * 1024 + lane * 16];

#define DSREAD(set, bi)                                      \
  {                                                          \
    aP[set][0] = *(const i64x2*)(lA0 + ((bi) << 12));        \
    aP[set][1] = *(const i64x2*)(lA0 + ((bi) << 12) + 1024); \
    bP[set][0] = *(const i64x2*)(lB0 + ((bi) << 12));        \
    bP[set][1] = *(const i64x2*)(lB0 + ((bi) << 12) + 1024); \
  }

  // ---- prologue: 3-deep stage prefetch (6 loads/thread in flight) ----
  STAGE(0, 0);
  STAGE(1, 1);
  STAGE(2, 2);
  asm volatile("s_waitcnt vmcnt(4)" ::: "memory");   // stage(0) landed
  __builtin_amdgcn_s_barrier();
  __builtin_amdgcn_sched_barrier(0);
  DSREAD(0, 0);

  // ---- pipelined K-loop ----
#pragma unroll
  for (int kt = 0; kt < 16; ++kt) {
    if (kt <= 13) {
      asm volatile("s_waitcnt vmcnt(2)" ::: "memory");  // stage(kt+1) landed
    } else {
      asm volatile("s_waitcnt vmcnt(0)" ::: "memory");
    }
    __builtin_amdgcn_s_barrier();
    __builtin_amdgcn_sched_barrier(0);

    if (kt <= 12) STAGE(kt + 3, (kt + 3) & 3);        // writer 2 iters behind
    if (kt < 15) DSREAD((kt + 1) & 1, (kt + 1) & 3);  // no wait; overlaps MFMA

    if (kt < 15) {
      asm volatile("s_waitcnt lgkmcnt(4)" ::: "memory"); // DSREAD(kt) done
    } else {
      asm volatile("s_waitcnt lgkmcnt(0)" ::: "memory");
    }
    __builtin_amdgcn_sched_barrier(0);

    {
      const int s = kt & 1;   // compile-time under full unroll
      long av[4] = {aP[s][0].x, aP[s][0].y, aP[s][1].x, aP[s][1].y};
      long bv[4] = {bP[s][0].x, bP[s][0].y, bP[s][1].x, bP[s][1].y};
      __builtin_amdgcn_s_setprio(1);
#pragma unroll
      for (int mf = 0; mf < 4; ++mf)
#pragma unroll
        for (int nf = 0; nf < 4; ++nf)
          acc[mf][nf] = __builtin_amdgcn_mfma_f32_16x16x32_fp8_fp8(
              av[mf], bv[nf], acc[mf][nf], 0, 0, 0);
      __builtin_amdgcn_s_setprio(0);
    }
  }
#undef STAGE
#undef DSREAD

  const float W = *wp;

  // ---- diag capture (raw cos) before exp consumes acc ----
  // block rows = speakers rb*4..+3; col c = rb*4+sp in this block iff
  // cb == c>>7 (= rb>>5, no carry since sp<4).
  if (cb == (rb >> 5)) {
#pragma unroll
    for (int sp = 0; sp < 4; ++sp) {
      const int c = rb * 4 + sp;
      if (wm == (sp >> 1) && wn == ((c >> 6) & 1)) {
        const int nfo = (c >> 4) & 3;
#pragma unroll
        for (int mh = 0; mh < 2; ++mh) {
          f32x4 dsel = acc[(sp & 1) * 2 + mh][0];
#pragma unroll
          for (int nf = 1; nf < 4; ++nf)
            if (nf == nfo) dsel = acc[(sp & 1) * 2 + mh][nf];  // static idx
          if (lr == (c & 15)) {
#pragma unroll
            for (int i = 0; i < 4; ++i)
              diag[c * 32 + mh * 16 + lk * 4 + i] = dsel[i];
          }
        }
      }
    }
  }

  // ---- fused epilogue: exp((fmax(cos,eps)-1)*W), reduce over 64 cols ----
#pragma unroll
  for (int mf = 0; mf < 4; ++mf)
#pragma unroll
    for (int i = 0; i < 4; ++i) {
      float s = 0.f;
#pragma unroll
      for (int nf = 0; nf < 4; ++nf)
        s += __expf((fmaxf(acc[mf][nf][i], EPS) - 1.f) * W);
      s += __shfl_xor(s, 1);
      s += __shfl_xor(s, 2);
      s += __shfl_xor(s, 4);
      s += __shfl_xor(s, 8);
      if (lr == 0) sPart[wm * 64 + mf * 16 + lk * 4 + i][wn] = s;
    }
  __syncthreads();
  if (t < 128)
    part[(size_t)cb * NROW + rb * 128 + t] = sPart[t][0] + sPart[t][1];
}

// ---------------------------------------------------------------------------
// Final: sum 8 col-chunk partials, swap exp(diag)->exp(loo), close lse,
// deterministic 2-stage sum.  L_row = log(s - exp(dt) + exp(lt)) - lt
// ---------------------------------------------------------------------------
__global__ __launch_bounds__(256) void k_final1(
    const float* __restrict__ part, const float* __restrict__ loo,
    const float* __restrict__ diag, const float* __restrict__ wp,
    float* __restrict__ p2)
{
  const int t = threadIdx.x;
  const int r = blockIdx.x * 256 + t;
  const float W = *wp;
  float s = 0.f;
#pragma unroll
  for (int c = 0; c < 8; ++c) s += part[(size_t)c * NROW + r];
  const float lt = (fmaxf(loo[r], EPS) - 1.f) * W;
  const float dt = (fmaxf(diag[r], EPS) - 1.f) * W;
  s += __expf(lt) - __expf(dt);
  float v = logf(s) - lt;
  __shared__ float red[4];
  for (int off = 32; off; off >>= 1) v += __shfl_down(v, off);
  if ((t & 63) == 0) red[t >> 6] = v;
  __syncthreads();
  if (t == 0) p2[blockIdx.x] = red[0] + red[1] + red[2] + red[3];
}

__global__ __launch_bounds__(128) void k_final2(
    const float* __restrict__ p2, float* __restrict__ out)
{
  const int t = threadIdx.x;
  float v = p2[t];
  for (int off = 32; off; off >>= 1) v += __shfl_down(v, off);
  __shared__ float red[2];
  if ((t & 63) == 0) red[t >> 6] = v;
  __syncthreads();
  if (t == 0) out[0] = red[0] + red[1];
}

extern "C" void kernel_launch(void* const* d_in, const int* in_sizes, int n_in,
                              void* d_out, int out_size, void* d_ws, size_t ws_size,
                              hipStream_t stream) {
  const float* dvecs = (const float*)d_in[0];
  const float* wptr  = (const float*)d_in[1];
  // b cancels algebraically (shift = w+b subtracted and re-added) -> unused
  float* out = (float*)d_out;

  char* ws = (char*)d_ws;
  char* Af8 = ws;            ws += (size_t)NROW * DIM;          // 16 MiB
  char* Bf8 = ws;            ws += (size_t)NSPK * DIM;          // 512 KiB
  float* loo  = (float*)ws;  ws += (size_t)NROW * sizeof(float);
  float* diag = (float*)ws;  ws += (size_t)NROW * sizeof(float);
  float* part = (float*)ws;  ws += (size_t)8 * NROW * sizeof(float);  // 1 MiB
  float* p2   = (float*)ws;

  k_prep<<<NSPK, 256, 0, stream>>>(dvecs, Af8, Bf8, loo);
  k_gemm<<<2048, 256, 0, stream>>>(Af8, Bf8, wptr, part, diag);
  k_final1<<<NROW / 256, 256, 0, stream>>>(part, loo, diag, wptr, p2);
  k_final2<<<1, 128, 0, stream>>>(p2, out);
}

// Round 19
// 61.844 us; speedup vs baseline: 1.7686x; 1.0703x over previous
//
#include <hip/hip_runtime.h>
#include <hip/hip_bf16.h>

#define NSPK 1024
#define MU 32
#define DIM 512
#define DIMP (DIM + 8)
#define NROW (NSPK * MU)   // 32768
#define EPS 1e-6f

typedef __attribute__((ext_vector_type(4))) float f32x4;
typedef __attribute__((ext_vector_type(2))) long i64x2;

#define GLOAD_LDS16(g, l)                                          \
  __builtin_amdgcn_global_load_lds(                                \
      (const __attribute__((address_space(1))) void*)(g),          \
      (__attribute__((address_space(3))) void*)(l), 16, 0, 0)

// ---------------------------------------------------------------------------
// Kernel 1: per-speaker prep. LOO cosines (fp32 exact) + normalized FP8-e4m3
// A and B blobs in step-major, pair-packed fragment layout:
//   A: [rb128][kt 16][rp 4][lane 64][pair 2][8B]  (64 KiB per 128-row block)
//   frag f = 2*rp+pair holds rows f*16..f*16+15; lane l: row = l&15,
//   k = kt*32 + (l>>4)*8 + z.  B identical with cols.
// R19: row staging via float4 (was 64 scalar loads/thread -- Common-mistake
// #2; 64 MB HBM read at ~2x inefficiency).
// grid = NSPK, block = 256
// ---------------------------------------------------------------------------
__global__ __launch_bounds__(256) void k_prep(
    const float* __restrict__ dvecs,
    char* __restrict__ Af8,     // [256][65536] bytes = 16 MiB
    char* __restrict__ Bf8,     // [8][65536] bytes = 512 KiB
    float* __restrict__ loo)    // [NROW]
{
  const int j = blockIdx.x, t = threadIdx.x;
  __shared__ float sD[MU * DIMP];   // padded raw speaker rows (66.5 KiB)
  __shared__ float4 sHalf[2][128];  // per-half float4 column sums (4 KiB)
  __shared__ float sS[DIM];
  __shared__ float sred[4];
  __shared__ float sS2v;
  __shared__ float sInv[MU];

  const float* base = dvecs + (size_t)j * (MU * DIM);

  // float4 staging: thread t -> row-half h (16 rows), float4-chunk c4
  const int h = t >> 7, c4 = t & 127;
  {
    const float* bp = base + h * 16 * DIM + c4 * 4;
    float4 cs = make_float4(0.f, 0.f, 0.f, 0.f);
#pragma unroll
    for (int m = 0; m < 16; ++m) {
      float4 v = *(const float4*)(bp + m * DIM);
      *(float4*)&sD[(h * 16 + m) * DIMP + c4 * 4] = v;
      cs.x += v.x; cs.y += v.y; cs.z += v.z; cs.w += v.w;
    }
    sHalf[h][c4] = cs;
  }
  __syncthreads();
  if (t < 128) {
    float4 a = sHalf[0][t], b2 = sHalf[1][t];
    float4 s;
    s.x = a.x + b2.x; s.y = a.y + b2.y; s.z = a.z + b2.z; s.w = a.w + b2.w;
    *(float4*)&sS[t * 4] = s;
  }
  __syncthreads();

  // |S|^2
  float p = sS[t] * sS[t] + sS[t + 256] * sS[t + 256];
  for (int off = 32; off; off >>= 1) p += __shfl_down(p, off);
  if ((t & 63) == 0) sred[t >> 6] = p;
  __syncthreads();
  if (t == 0) sS2v = sred[0] + sred[1] + sred[2] + sred[3];
  __syncthreads();
  const float S2 = sS2v;

  // per-utterance dot(e,S), |e|^2 from LDS (8 lanes per row)
  const int g = t >> 3, l = t & 7;
  float dotS = 0.f, e2 = 0.f;
  for (int i = 0; i < DIM / 8; ++i) {
    int d = i * 8 + l;
    float ev = sD[g * DIMP + d];
    dotS += ev * sS[d];
    e2 += ev * ev;
  }
  for (int off = 4; off; off >>= 1) {
    dotS += __shfl_down(dotS, off);
    e2 += __shfl_down(e2, off);
  }
  if (l == 0) {
    float numer = dotS - e2;                          // e.(S-e)
    float d2 = fmaxf(S2 - 2.f * dotS + e2, 1e-30f);   // |S-e|^2
    loo[j * MU + g] = numer / (sqrtf(e2) * sqrtf(d2));
    sInv[g] = 1.f / sqrtf(e2);
  }
  __syncthreads();

  // A fp8 blob: speaker j = rows (j&3)*32..+31 of rb128 = j>>2.
  for (int i = 0; i < 8; ++i) {
    int idx = i * 256 + t;        // 0..2047
    int m = idx >> 6;             // utterance 0..31
    int c = idx & 63;             // 8-elem k-chunk
    int kt = c >> 2, lk = c & 3;
    float inv = sInv[m];
    const float* src = &sD[m * DIMP + c * 8];
    int b0 = 0, b1 = 0;
    b0 = __builtin_amdgcn_cvt_pk_fp8_f32(src[0] * inv, src[1] * inv, b0, false);
    b0 = __builtin_amdgcn_cvt_pk_fp8_f32(src[2] * inv, src[3] * inv, b0, true);
    b1 = __builtin_amdgcn_cvt_pk_fp8_f32(src[4] * inv, src[5] * inv, b1, false);
    b1 = __builtin_amdgcn_cvt_pk_fp8_f32(src[6] * inv, src[7] * inv, b1, true);
    size_t byte = ((size_t)(j >> 2) << 16) + ((size_t)kt << 12) +
                  ((size_t)(j & 3) << 10) + (lk * 16 + (m & 15)) * 16 +
                  (((m >> 4) & 1) << 3);
    *(int2*)(Af8 + byte) = make_int2(b0, b1);
  }

  // B fp8 blob: centroid j -> nb128 = j>>7, cp = (j>>5)&3, pair = (j>>4)&1.
  if (t < 64) {
    int c = t;                    // k-chunk 0..63
    int kt = c >> 2, lk = c & 3;
    float invc = 1.f / sqrtf(S2);
    const float* src = &sS[c * 8];
    int b0 = 0, b1 = 0;
    b0 = __builtin_amdgcn_cvt_pk_fp8_f32(src[0] * invc, src[1] * invc, b0, false);
    b0 = __builtin_amdgcn_cvt_pk_fp8_f32(src[2] * invc, src[3] * invc, b0, true);
    b1 = __builtin_amdgcn_cvt_pk_fp8_f32(src[4] * invc, src[5] * invc, b1, false);
    b1 = __builtin_amdgcn_cvt_pk_fp8_f32(src[6] * invc, src[7] * invc, b1, true);
    size_t byte = ((size_t)(j >> 7) << 16) + ((size_t)kt << 12) +
                  ((size_t)((j >> 5) & 3) << 10) + (lk * 16 + (j & 15)) * 16 +
                  (((j >> 4) & 1) << 3);
    *(int2*)(Bf8 + byte) = make_int2(b0, b1);
  }
}

// ---------------------------------------------------------------------------
// Kernel 2: FP8 MFMA tiled GEMM, 6-buffer counted-vmcnt pipeline,
// TWO K-tiles per barrier-round (8 rounds instead of 16).
// Tile 128x128, 256 thr (4 waves, 2wm x 2wn), wave tile 64x64 (acc[4][4]).
// R18 post-mortem: fp8 bought 49.5->41.3 but MfmaUtil stalled at 30% --
// the 16-per-block barrier-round scaffold now dominates the (halved)
// per-step work. This round halves rounds: per round consume tiles
// 2i,2i+1 (8 ds_read_b128, 32 MFMA in two setprio clusters, counted
// lgkm(4) between), stage tiles 2i+4,2i+5 (4 loads/thread). 6-buf
// rotation: writer tile 2i+6 (round i+1) overwrites tile-2i's buf, whose
// reads completed at round i's lgkm(0) -- safe via round-i+1 barrier.
// vmcnt ledger: prologue tiles 0-3 (8 loads); round i waits vmcnt(4)
// (= tiles 2i,2i+1 landed), rounds 0..5 stage. LDS 49 KiB -> 3 blocks/CU.
// Grid 2048 = 256 rb x 8 cb, XCD-chunked swizzle (32-rb band per XCD).
// ---------------------------------------------------------------------------
__global__ __launch_bounds__(256, 1) void k_gemm(
    const char* __restrict__ Af8,
    const char* __restrict__ Bf8,
    const float* __restrict__ wp,
    float* __restrict__ part,    // [8][NROW] partial sumexp per col-chunk
    float* __restrict__ diag)    // [NROW] raw cos vs own full centroid
{
  __shared__ char ldsA[6 * 4096];   // 24 KiB: 6 bufs x 4 KiB tile
  __shared__ char ldsB[6 * 4096];   // 24 KiB
  __shared__ float sPart[128][2];   // 1 KiB

  const int t = threadIdx.x;
  const int w = t >> 6, lane = t & 63;
  const int lr = lane & 15, lk = lane >> 4;
  const int wm = w >> 1, wn = w & 1;      // 2 x 2 wave grid
  // XCD-chunked block swizzle
  const int bid = blockIdx.x;
  const int xcd = bid & 7, ii = bid >> 3;     // ii in [0,256) per XCD
  const int rb = xcd * 32 + (ii >> 3);        // 0..255 (128 rows each)
  const int cb = ii & 7;                      // 0..7   (128 cols each)

  f32x4 acc[4][4];
#pragma unroll
  for (int a = 0; a < 4; ++a)
#pragma unroll
    for (int b = 0; b < 4; ++b) acc[a][b] = (f32x4)0.f;

  // staging: one 16B chunk per thread per tile (A and B)
  const char* gA = Af8 + ((size_t)rb << 16) + t * 16;
  const char* gB = Bf8 + ((size_t)cb << 16) + t * 16;
  char* dA = &ldsA[t * 16];
  char* dB = &ldsB[t * 16];

#define STAGE(kt, bi)                                          \
  {                                                            \
    GLOAD_LDS16(gA + ((size_t)(kt) << 12), dA + ((bi) << 12)); \
    GLOAD_LDS16(gB + ((size_t)(kt) << 12), dB + ((bi) << 12)); \
  }

  // two fragment register sets; each b128 = 2 fp8 frags (a pair)
  i64x2 aP[2][2], bP[2][2];
  const char* lA0 = &ldsA[(wm * 2) * 1024 + lane * 16];
  const char* lB0 = &ldsB[(wn * 2) * 1024 + lane * 16];

#define DSREAD(set, bi)                                      \
  {                                                          \
    aP[set][0] = *(const i64x2*)(lA0 + ((bi) << 12));        \
    aP[set][1] = *(const i64x2*)(lA0 + ((bi) << 12) + 1024); \
    bP[set][0] = *(const i64x2*)(lB0 + ((bi) << 12));        \
    bP[set][1] = *(const i64x2*)(lB0 + ((bi) << 12) + 1024); \
  }

#define MFMA_SET(s)                                                      \
  {                                                                      \
    long av[4] = {aP[s][0].x, aP[s][0].y, aP[s][1].x, aP[s][1].y};       \
    long bv[4] = {bP[s][0].x, bP[s][0].y, bP[s][1].x, bP[s][1].y};       \
    __builtin_amdgcn_s_setprio(1);                                       \
    _Pragma("unroll")                                                    \
    for (int mf = 0; mf < 4; ++mf)                                       \
      _Pragma("unroll")                                                  \
      for (int nf = 0; nf < 4; ++nf)                                     \
        acc[mf][nf] = __builtin_amdgcn_mfma_f32_16x16x32_fp8_fp8(        \
            av[mf], bv[nf], acc[mf][nf], 0, 0, 0);                       \
    __builtin_amdgcn_s_setprio(0);                                       \
  }

  // ---- prologue: tiles 0-3 staged (8 loads/thread in flight) ----
  STAGE(0, 0);
  STAGE(1, 1);
  STAGE(2, 2);
  STAGE(3, 3);

  // ---- pipelined K-loop: 8 barrier-rounds, 2 tiles each ----
#pragma unroll
  for (int i = 0; i < 8; ++i) {
    if (i < 7) {
      asm volatile("s_waitcnt vmcnt(4)" ::: "memory");  // tiles 2i,2i+1 in
    } else {
      asm volatile("s_waitcnt vmcnt(0)" ::: "memory");
    }
    __builtin_amdgcn_s_barrier();
    __builtin_amdgcn_sched_barrier(0);

    if (i <= 5) {
      STAGE(2 * i + 4, (2 * i + 4) % 6);
      STAGE(2 * i + 5, (2 * i + 5) % 6);
    }

    DSREAD(0, (2 * i) % 6);
    __builtin_amdgcn_sched_barrier(0);    // pin set-0 reads first
    DSREAD(1, (2 * i + 1) % 6);

    asm volatile("s_waitcnt lgkmcnt(4)" ::: "memory");  // set-0 reads done
    __builtin_amdgcn_sched_barrier(0);
    MFMA_SET(0);
    asm volatile("s_waitcnt lgkmcnt(0)" ::: "memory");  // set-1 reads done
    __builtin_amdgcn_sched_barrier(0);
    MFMA_SET(1);
  }
#undef STAGE
#undef DSREAD
#undef MFMA_SET

  const float W = *wp;

  // ---- diag capture (raw cos) before exp consumes acc ----
  // block rows = speakers rb*4..+3; col c = rb*4+sp in this block iff
  // cb == c>>7 (= rb>>5, no carry since sp<4).
  if (cb == (rb >> 5)) {
#pragma unroll
    for (int sp = 0; sp < 4; ++sp) {
      const int c = rb * 4 + sp;
      if (wm == (sp >> 1) && wn == ((c >> 6) & 1)) {
        const int nfo = (c >> 4) & 3;
#pragma unroll
        for (int mh = 0; mh < 2; ++mh) {
          f32x4 dsel = acc[(sp & 1) * 2 + mh][0];
#pragma unroll
          for (int nf = 1; nf < 4; ++nf)
            if (nf == nfo) dsel = acc[(sp & 1) * 2 + mh][nf];  // static idx
          if (lr == (c & 15)) {
#pragma unroll
            for (int i = 0; i < 4; ++i)
              diag[c * 32 + mh * 16 + lk * 4 + i] = dsel[i];
          }
        }
      }
    }
  }

  // ---- fused epilogue: exp((fmax(cos,eps)-1)*W), reduce over 64 cols ----
#pragma unroll
  for (int mf = 0; mf < 4; ++mf)
#pragma unroll
    for (int i = 0; i < 4; ++i) {
      float s = 0.f;
#pragma unroll
      for (int nf = 0; nf < 4; ++nf)
        s += __expf((fmaxf(acc[mf][nf][i], EPS) - 1.f) * W);
      s += __shfl_xor(s, 1);
      s += __shfl_xor(s, 2);
      s += __shfl_xor(s, 4);
      s += __shfl_xor(s, 8);
      if (lr == 0) sPart[wm * 64 + mf * 16 + lk * 4 + i][wn] = s;
    }
  __syncthreads();
  if (t < 128)
    part[(size_t)cb * NROW + rb * 128 + t] = sPart[t][0] + sPart[t][1];
}

// ---------------------------------------------------------------------------
// Final: sum 8 col-chunk partials, swap exp(diag)->exp(loo), close lse,
// deterministic 2-stage sum.  L_row = log(s - exp(dt) + exp(lt)) - lt
// ---------------------------------------------------------------------------
__global__ __launch_bounds__(256) void k_final1(
    const float* __restrict__ part, const float* __restrict__ loo,
    const float* __restrict__ diag, const float* __restrict__ wp,
    float* __restrict__ p2)
{
  const int t = threadIdx.x;
  const int r = blockIdx.x * 256 + t;
  const float W = *wp;
  float s = 0.f;
#pragma unroll
  for (int c = 0; c < 8; ++c) s += part[(size_t)c * NROW + r];
  const float lt = (fmaxf(loo[r], EPS) - 1.f) * W;
  const float dt = (fmaxf(diag[r], EPS) - 1.f) * W;
  s += __expf(lt) - __expf(dt);
  float v = logf(s) - lt;
  __shared__ float red[4];
  for (int off = 32; off; off >>= 1) v += __shfl_down(v, off);
  if ((t & 63) == 0) red[t >> 6] = v;
  __syncthreads();
  if (t == 0) p2[blockIdx.x] = red[0] + red[1] + red[2] + red[3];
}

__global__ __launch_bounds__(128) void k_final2(
    const float* __restrict__ p2, float* __restrict__ out)
{
  const int t = threadIdx.x;
  float v = p2[t];
  for (int off = 32; off; off >>= 1) v += __shfl_down(v, off);
  __shared__ float red[2];
  if ((t & 63) == 0) red[t >> 6] = v;
  __syncthreads();
  if (t == 0) out[0] = red[0] + red[1];
}

extern "C" void kernel_launch(void* const* d_in, const int* in_sizes, int n_in,
                              void* d_out, int out_size, void* d_ws, size_t ws_size,
                              hipStream_t stream) {
  const float* dvecs = (const float*)d_in[0];
  const float* wptr  = (const float*)d_in[1];
  // b cancels algebraically (shift = w+b subtracted and re-added) -> unused
  float* out = (float*)d_out;

  char* ws = (char*)d_ws;
  char* Af8 = ws;            ws += (size_t)NROW * DIM;          // 16 MiB
  char* Bf8 = ws;            ws += (size_t)NSPK * DIM;          // 512 KiB
  float* loo  = (float*)ws;  ws += (size_t)NROW * sizeof(float);
  float* diag = (float*)ws;  ws += (size_t)NROW * sizeof(float);
  float* part = (float*)ws;  ws += (size_t)8 * NROW * sizeof(float);  // 1 MiB
  float* p2   = (float*)ws;

  k_prep<<<NSPK, 256, 0, stream>>>(dvecs, Af8, Bf8, loo);
  k_gemm<<<2048, 256, 0, stream>>>(Af8, Bf8, wptr, part, diag);
  k_final1<<<NROW / 256, 256, 0, stream>>>(part, loo, diag, wptr, p2);
  k_final2<<<1, 128, 0, stream>>>(p2, out);
}

// Round 20
// 59.927 us; speedup vs baseline: 1.8252x; 1.0320x over previous
//
#include <hip/hip_runtime.h>
#include <hip/hip_bf16.h>

#define NSPK 1024
#define MU 32
#define DIM 512
#define DIMP (DIM + 8)
#define NROW (NSPK * MU)   // 32768
#define EPS 1e-6f

typedef __attribute__((ext_vector_type(4))) float f32x4;
typedef __attribute__((ext_vector_type(8))) int i32x8;

#define GLOAD_LDS16(g, l)                                          \
  __builtin_amdgcn_global_load_lds(                                \
      (const __attribute__((address_space(1))) void*)(g),          \
      (__attribute__((address_space(3))) void*)(l), 16, 0, 0)

#define UNIT_SCALE 0x7F7F7F7F   // E8M0 127 = x1.0 in every byte (opsel-proof)

// ---------------------------------------------------------------------------
// Kernel 1: per-speaker prep. LOO cosines (fp32 exact) + normalized FP8-e4m3
// blobs for the K=128 scaled MFMA. Tile (rb128, kt128) = 16 KiB:
//   [rp 8][lane 64][32 B]; frag rp covers rows rp*16..+15; lane l:
//   row = l&15, k = kt*128 + (l>>4)*32 + z, z in [0,32).
// A: [256 rb][4 kt][16 KiB] = 16 MiB.  B: [8 nb][4 kt][16 KiB] = 512 KiB.
// (Any consistent A/B k-convention is valid -- dot is k-permutation
// invariant; scales are uniform 1.0.)
// grid = NSPK, block = 256
// ---------------------------------------------------------------------------
__global__ __launch_bounds__(256) void k_prep(
    const float* __restrict__ dvecs,
    char* __restrict__ Af8,
    char* __restrict__ Bf8,
    float* __restrict__ loo)    // [NROW]
{
  const int j = blockIdx.x, t = threadIdx.x;
  __shared__ float sD[MU * DIMP];   // padded raw speaker rows (66.5 KiB)
  __shared__ float4 sHalf[2][128];  // per-half float4 column sums (4 KiB)
  __shared__ float sS[DIM];
  __shared__ float sred[4];
  __shared__ float sS2v;
  __shared__ float sInv[MU];

  const float* base = dvecs + (size_t)j * (MU * DIM);

  // float4 staging: thread t -> row-half h (16 rows), float4-chunk c4
  const int h = t >> 7, c4 = t & 127;
  {
    const float* bp = base + h * 16 * DIM + c4 * 4;
    float4 cs = make_float4(0.f, 0.f, 0.f, 0.f);
#pragma unroll
    for (int m = 0; m < 16; ++m) {
      float4 v = *(const float4*)(bp + m * DIM);
      *(float4*)&sD[(h * 16 + m) * DIMP + c4 * 4] = v;
      cs.x += v.x; cs.y += v.y; cs.z += v.z; cs.w += v.w;
    }
    sHalf[h][c4] = cs;
  }
  __syncthreads();
  if (t < 128) {
    float4 a = sHalf[0][t], b2 = sHalf[1][t];
    float4 s;
    s.x = a.x + b2.x; s.y = a.y + b2.y; s.z = a.z + b2.z; s.w = a.w + b2.w;
    *(float4*)&sS[t * 4] = s;
  }
  __syncthreads();

  // |S|^2
  float p = sS[t] * sS[t] + sS[t + 256] * sS[t + 256];
  for (int off = 32; off; off >>= 1) p += __shfl_down(p, off);
  if ((t & 63) == 0) sred[t >> 6] = p;
  __syncthreads();
  if (t == 0) sS2v = sred[0] + sred[1] + sred[2] + sred[3];
  __syncthreads();
  const float S2 = sS2v;

  // per-utterance dot(e,S), |e|^2 from LDS (8 lanes per row)
  const int g = t >> 3, l = t & 7;
  float dotS = 0.f, e2 = 0.f;
  for (int i = 0; i < DIM / 8; ++i) {
    int d = i * 8 + l;
    float ev = sD[g * DIMP + d];
    dotS += ev * sS[d];
    e2 += ev * ev;
  }
  for (int off = 4; off; off >>= 1) {
    dotS += __shfl_down(dotS, off);
    e2 += __shfl_down(e2, off);
  }
  if (l == 0) {
    float numer = dotS - e2;                          // e.(S-e)
    float d2 = fmaxf(S2 - 2.f * dotS + e2, 1e-30f);   // |S-e|^2
    loo[j * MU + g] = numer / (sqrtf(e2) * sqrtf(d2));
    sInv[g] = 1.f / sqrtf(e2);
  }
  __syncthreads();

  // A blob: speaker j -> rb = j>>2; utterance m -> rp = (j&3)*2 + (m>>4).
  // 1024 16-B chunks: idx = (m 5b)(kt 2b)(kslot 2b)(half 1b)
  for (int i = 0; i < 4; ++i) {
    int idx = i * 256 + t;
    int m = idx >> 5;
    int c = idx & 31;
    int kt = c >> 3, kslot = (c >> 1) & 3, half = c & 1;
    float inv = sInv[m];
    const float* src = &sD[m * DIMP + kt * 128 + kslot * 32 + half * 16];
    int b0 = 0, b1 = 0, b2 = 0, b3 = 0;
    b0 = __builtin_amdgcn_cvt_pk_fp8_f32(src[0] * inv, src[1] * inv, b0, false);
    b0 = __builtin_amdgcn_cvt_pk_fp8_f32(src[2] * inv, src[3] * inv, b0, true);
    b1 = __builtin_amdgcn_cvt_pk_fp8_f32(src[4] * inv, src[5] * inv, b1, false);
    b1 = __builtin_amdgcn_cvt_pk_fp8_f32(src[6] * inv, src[7] * inv, b1, true);
    b2 = __builtin_amdgcn_cvt_pk_fp8_f32(src[8] * inv, src[9] * inv, b2, false);
    b2 = __builtin_amdgcn_cvt_pk_fp8_f32(src[10] * inv, src[11] * inv, b2, true);
    b3 = __builtin_amdgcn_cvt_pk_fp8_f32(src[12] * inv, src[13] * inv, b3, false);
    b3 = __builtin_amdgcn_cvt_pk_fp8_f32(src[14] * inv, src[15] * inv, b3, true);
    int rp = (j & 3) * 2 + (m >> 4);
    int lane2 = kslot * 16 + (m & 15);
    size_t byte = (((size_t)(j >> 2) * 4 + kt) << 14) + rp * 2048 +
                  lane2 * 32 + half * 16;
    *(int4*)(Af8 + byte) = make_int4(b0, b1, b2, b3);
  }

  // B blob: centroid j -> nb = j>>7, rp = (j>>4)&7, lanes kslot*16+(j&15).
  if (t < 32) {
    int c = t;
    int kt = c >> 3, kslot = (c >> 1) & 3, half = c & 1;
    float invc = 1.f / sqrtf(S2);
    const float* src = &sS[kt * 128 + kslot * 32 + half * 16];
    int b0 = 0, b1 = 0, b2 = 0, b3 = 0;
    b0 = __builtin_amdgcn_cvt_pk_fp8_f32(src[0] * invc, src[1] * invc, b0, false);
    b0 = __builtin_amdgcn_cvt_pk_fp8_f32(src[2] * invc, src[3] * invc, b0, true);
    b1 = __builtin_amdgcn_cvt_pk_fp8_f32(src[4] * invc, src[5] * invc, b1, false);
    b1 = __builtin_amdgcn_cvt_pk_fp8_f32(src[6] * invc, src[7] * invc, b1, true);
    b2 = __builtin_amdgcn_cvt_pk_fp8_f32(src[8] * invc, src[9] * invc, b2, false);
    b2 = __builtin_amdgcn_cvt_pk_fp8_f32(src[10] * invc, src[11] * invc, b2, true);
    b3 = __builtin_amdgcn_cvt_pk_fp8_f32(src[12] * invc, src[13] * invc, b3, false);
    b3 = __builtin_amdgcn_cvt_pk_fp8_f32(src[14] * invc, src[15] * invc, b3, true);
    int rp = (j >> 4) & 7;
    int lane2 = kslot * 16 + (j & 15);
    size_t byte = (((size_t)(j >> 7) * 4 + kt) << 14) + rp * 2048 +
                  lane2 * 32 + half * 16;
    *(int4*)(Bf8 + byte) = make_int4(b0, b1, b2, b3);
  }
}

// ---------------------------------------------------------------------------
// Kernel 2: MX-scaled fp8 K=128 MFMA GEMM (unit scales), 2-buffer pipeline.
// Tile 128x128, BK=128 -> only 4 K-steps (4 barrier rounds; scaffold tax
// quartered vs R18). 256 thr (4 waves, 2wm x 2wn), wave tile 64x64:
// acc[4][4] f32x4 = 64 AGPR (the proven no-spill shape) + a8/b8 frag regs
// 64 + addr ~30 -> 2-3 waves/SIMD.
// mfma_scale_f32_16x16x128_f8f6f4 @ 2x non-scaled fp8 rate (4661 TF) with
// scales = 0x7F7F7F7F (E8M0 127 = x1.0 in all bytes -> opsel-proof;
// numerics identical to R18/R19). A/B share the k-convention -> any
// internal k-permutation of the instruction is harmless.
// Per round: vmcnt(0) (tile landed; staged a full round ago), barrier,
// STAGE(next) into alternate buf (readers drained at prev round's
// lgkm(0), ordered by this barrier), 16 ds_read_b128 (lane-stride 32 B =
// 2-way alias = free), lgkm(0), 16 MFMA under setprio.
// LDS 2x(16+16) KiB + 1 = 65 KiB -> 2 blocks/CU.
// Grid 2048 = 256 rb x 8 cb, XCD-chunked swizzle (32-rb band per XCD).
// ---------------------------------------------------------------------------
__global__ __launch_bounds__(256, 1) void k_gemm(
    const char* __restrict__ Af8,
    const char* __restrict__ Bf8,
    const float* __restrict__ wp,
    float* __restrict__ part,    // [8][NROW] partial sumexp per col-chunk
    float* __restrict__ diag)    // [NROW] raw cos vs own full centroid
{
  __shared__ char ldsA[2 * 16384];  // 32 KiB: 2 bufs x 16 KiB K-tile
  __shared__ char ldsB[2 * 16384];  // 32 KiB
  __shared__ float sPart[128][2];   // 1 KiB

  const int t = threadIdx.x;
  const int w = t >> 6, lane = t & 63;
  const int lr = lane & 15, lk = lane >> 4;
  const int wm = w >> 1, wn = w & 1;      // 2 x 2 wave grid
  // XCD-chunked block swizzle
  const int bid = blockIdx.x;
  const int xcd = bid & 7, ii = bid >> 3;     // ii in [0,256) per XCD
  const int rb = xcd * 32 + (ii >> 3);        // 0..255 (128 rows each)
  const int cb = ii & 7;                      // 0..7   (128 cols each)

  f32x4 acc[4][4];
#pragma unroll
  for (int a = 0; a < 4; ++a)
#pragma unroll
    for (int b = 0; b < 4; ++b) acc[a][b] = (f32x4)0.f;

  // staging: 16 KiB per tile per operand = 4 gload16/thread each
  const char* gA = Af8 + ((size_t)rb << 16) + t * 16;
  const char* gB = Bf8 + ((size_t)cb << 16) + t * 16;
  char* dA = &ldsA[t * 16];
  char* dB = &ldsB[t * 16];

#define STAGE(kt, bi)                                                        \
  {                                                                          \
    _Pragma("unroll")                                                        \
    for (int q = 0; q < 4; ++q) {                                            \
      GLOAD_LDS16(gA + ((size_t)(kt) << 14) + q * 4096,                      \
                  dA + ((bi) << 14) + q * 4096);                             \
      GLOAD_LDS16(gB + ((size_t)(kt) << 14) + q * 4096,                      \
                  dB + ((bi) << 14) + q * 4096);                             \
    }                                                                        \
  }

  const char* lA0 = &ldsA[(wm * 4) * 2048 + lane * 32];
  const char* lB0 = &ldsB[(wn * 4) * 2048 + lane * 32];

  // ---- prologue ----
  STAGE(0, 0);

  // ---- K-loop: 4 rounds ----
#pragma unroll
  for (int kt = 0; kt < 4; ++kt) {
    asm volatile("s_waitcnt vmcnt(0)" ::: "memory");  // tile kt landed
    __builtin_amdgcn_s_barrier();
    __builtin_amdgcn_sched_barrier(0);

    if (kt < 3) STAGE(kt + 1, (kt + 1) & 1);

    // 16 ds_read_b128: 4 A-frags + 4 B-frags, 32 B each (2 reads/frag)
    i32x8 a8[4], b8[4];
#pragma unroll
    for (int f = 0; f < 4; ++f) {
      int4 lo = *(const int4*)(lA0 + ((kt & 1) << 14) + f * 2048);
      int4 hi = *(const int4*)(lA0 + ((kt & 1) << 14) + f * 2048 + 16);
      a8[f][0] = lo.x; a8[f][1] = lo.y; a8[f][2] = lo.z; a8[f][3] = lo.w;
      a8[f][4] = hi.x; a8[f][5] = hi.y; a8[f][6] = hi.z; a8[f][7] = hi.w;
    }
#pragma unroll
    for (int f = 0; f < 4; ++f) {
      int4 lo = *(const int4*)(lB0 + ((kt & 1) << 14) + f * 2048);
      int4 hi = *(const int4*)(lB0 + ((kt & 1) << 14) + f * 2048 + 16);
      b8[f][0] = lo.x; b8[f][1] = lo.y; b8[f][2] = lo.z; b8[f][3] = lo.w;
      b8[f][4] = hi.x; b8[f][5] = hi.y; b8[f][6] = hi.z; b8[f][7] = hi.w;
    }

    asm volatile("s_waitcnt lgkmcnt(0)" ::: "memory");
    __builtin_amdgcn_sched_barrier(0);

    __builtin_amdgcn_s_setprio(1);
#pragma unroll
    for (int mf = 0; mf < 4; ++mf)
#pragma unroll
      for (int nf = 0; nf < 4; ++nf)
        acc[mf][nf] = __builtin_amdgcn_mfma_scale_f32_16x16x128_f8f6f4(
            a8[mf], b8[nf], acc[mf][nf],
            0, 0,                       // cbsz=fp8(e4m3), blgp=fp8(e4m3)
            0, UNIT_SCALE,              // opselA, scaleA (x1.0)
            0, UNIT_SCALE);             // opselB, scaleB (x1.0)
    __builtin_amdgcn_s_setprio(0);
  }
#undef STAGE

  const float W = *wp;

  // ---- diag capture (raw cos) before exp consumes acc ----
  // block rows = speakers rb*4..+3; col c = rb*4+sp in this block iff
  // cb == c>>7 (= rb>>5, no carry since sp<4).
  if (cb == (rb >> 5)) {
#pragma unroll
    for (int sp = 0; sp < 4; ++sp) {
      const int c = rb * 4 + sp;
      if (wm == (sp >> 1) && wn == ((c >> 6) & 1)) {
        const int nfo = (c >> 4) & 3;
#pragma unroll
        for (int mh = 0; mh < 2; ++mh) {
          f32x4 dsel = acc[(sp & 1) * 2 + mh][0];
#pragma unroll
          for (int nf = 1; nf < 4; ++nf)
            if (nf == nfo) dsel = acc[(sp & 1) * 2 + mh][nf];  // static idx
          if (lr == (c & 15)) {
#pragma unroll
            for (int i = 0; i < 4; ++i)
              diag[c * 32 + mh * 16 + lk * 4 + i] = dsel[i];
          }
        }
      }
    }
  }

  // ---- fused epilogue: exp((fmax(cos,eps)-1)*W), reduce over 64 cols ----
#pragma unroll
  for (int mf = 0; mf < 4; ++mf)
#pragma unroll
    for (int i = 0; i < 4; ++i) {
      float s = 0.f;
#pragma unroll
      for (int nf = 0; nf < 4; ++nf)
        s += __expf((fmaxf(acc[mf][nf][i], EPS) - 1.f) * W);
      s += __shfl_xor(s, 1);
      s += __shfl_xor(s, 2);
      s += __shfl_xor(s, 4);
      s += __shfl_xor(s, 8);
      if (lr == 0) sPart[wm * 64 + mf * 16 + lk * 4 + i][wn] = s;
    }
  __syncthreads();
  if (t < 128)
    part[(size_t)cb * NROW + rb * 128 + t] = sPart[t][0] + sPart[t][1];
}

// ---------------------------------------------------------------------------
// Final: sum 8 col-chunk partials, swap exp(diag)->exp(loo), close lse,
// deterministic 2-stage sum.  L_row = log(s - exp(dt) + exp(lt)) - lt
// ---------------------------------------------------------------------------
__global__ __launch_bounds__(256) void k_final1(
    const float* __restrict__ part, const float* __restrict__ loo,
    const float* __restrict__ diag, const float* __restrict__ wp,
    float* __restrict__ p2)
{
  const int t = threadIdx.x;
  const int r = blockIdx.x * 256 + t;
  const float W = *wp;
  float s = 0.f;
#pragma unroll
  for (int c = 0; c < 8; ++c) s += part[(size_t)c * NROW + r];
  const float lt = (fmaxf(loo[r], EPS) - 1.f) * W;
  const float dt = (fmaxf(diag[r], EPS) - 1.f) * W;
  s += __expf(lt) - __expf(dt);
  float v = logf(s) - lt;
  __shared__ float red[4];
  for (int off = 32; off; off >>= 1) v += __shfl_down(v, off);
  if ((t & 63) == 0) red[t >> 6] = v;
  __syncthreads();
  if (t == 0) p2[blockIdx.x] = red[0] + red[1] + red[2] + red[3];
}

__global__ __launch_bounds__(128) void k_final2(
    const float* __restrict__ p2, float* __restrict__ out)
{
  const int t = threadIdx.x;
  float v = p2[t];
  for (int off = 32; off; off >>= 1) v += __shfl_down(v, off);
  __shared__ float red[2];
  if ((t & 63) == 0) red[t >> 6] = v;
  __syncthreads();
  if (t == 0) out[0] = red[0] + red[1];
}

extern "C" void kernel_launch(void* const* d_in, const int* in_sizes, int n_in,
                              void* d_out, int out_size, void* d_ws, size_t ws_size,
                              hipStream_t stream) {
  const float* dvecs = (const float*)d_in[0];
  const float* wptr  = (const float*)d_in[1];
  // b cancels algebraically (shift = w+b subtracted and re-added) -> unused
  float* out = (float*)d_out;

  char* ws = (char*)d_ws;
  char* Af8 = ws;            ws += (size_t)NROW * DIM;          // 16 MiB
  char* Bf8 = ws;            ws += (size_t)NSPK * DIM;          // 512 KiB
  float* loo  = (float*)ws;  ws += (size_t)NROW * sizeof(float);
  float* diag = (float*)ws;  ws += (size_t)NROW * sizeof(float);
  float* part = (float*)ws;  ws += (size_t)8 * NROW * sizeof(float);  // 1 MiB
  float* p2   = (float*)ws;

  k_prep<<<NSPK, 256, 0, stream>>>(dvecs, Af8, Bf8, loo);
  k_gemm<<<2048, 256, 0, stream>>>(Af8, Bf8, wptr, part, diag);
  k_final1<<<NROW / 256, 256, 0, stream>>>(part, loo, diag, wptr, p2);
  k_final2<<<1, 128, 0, stream>>>(p2, out);
}

// Round 21
// 58.896 us; speedup vs baseline: 1.8571x; 1.0175x over previous
//
#include <hip/hip_runtime.h>
#include <hip/hip_bf16.h>

#define NSPK 1024
#define MU 32
#define DIM 512
#define DIMP (DIM + 8)
#define NROW (NSPK * MU)   // 32768
#define EPS 1e-6f

typedef __attribute__((ext_vector_type(4))) float f32x4;
typedef __attribute__((ext_vector_type(8))) int i32x8;

#define GLOAD_LDS16(g, l)                                          \
  __builtin_amdgcn_global_load_lds(                                \
      (const __attribute__((address_space(1))) void*)(g),          \
      (__attribute__((address_space(3))) void*)(l), 16, 0, 0)

#define UNIT_SCALE 0x7F7F7F7F   // E8M0 127 = x1.0 in every byte (opsel-proof)

// ---------------------------------------------------------------------------
// Kernel 1: per-speaker prep. LOO cosines (fp32 exact) + normalized FP8-e4m3
// blobs for the K=128 scaled MFMA. Tile (rb128, kt128) = 16 KiB, fragment
// rp = 2048 B stored as SPLIT HALF-PLANES (R20 fix: lane*32 reads were a
// 16-way bank conflict, 2.1M conflicts/dispatch):
//   byte = rp*2048 + half*1024 + lane*16 ; lane l: row = l&15,
//   k = kt*128 + (l>>4)*32 + half*16 + [0,16).
// A: [256 rb][4 kt][16 KiB] = 16 MiB.  B: [8 nb][4 kt][16 KiB] = 512 KiB.
// (A/B share the k-convention -> dot is k-permutation invariant; scales
// uniform 1.0.)
// grid = NSPK, block = 256
// ---------------------------------------------------------------------------
__global__ __launch_bounds__(256) void k_prep(
    const float* __restrict__ dvecs,
    char* __restrict__ Af8,
    char* __restrict__ Bf8,
    float* __restrict__ loo)    // [NROW]
{
  const int j = blockIdx.x, t = threadIdx.x;
  __shared__ float sD[MU * DIMP];   // padded raw speaker rows (66.5 KiB)
  __shared__ float4 sHalf[2][128];  // per-half float4 column sums (4 KiB)
  __shared__ float sS[DIM];
  __shared__ float sred[4];
  __shared__ float sS2v;
  __shared__ float sInv[MU];

  const float* base = dvecs + (size_t)j * (MU * DIM);

  // float4 staging: thread t -> row-half h (16 rows), float4-chunk c4
  const int h = t >> 7, c4 = t & 127;
  {
    const float* bp = base + h * 16 * DIM + c4 * 4;
    float4 cs = make_float4(0.f, 0.f, 0.f, 0.f);
#pragma unroll
    for (int m = 0; m < 16; ++m) {
      float4 v = *(const float4*)(bp + m * DIM);
      *(float4*)&sD[(h * 16 + m) * DIMP + c4 * 4] = v;
      cs.x += v.x; cs.y += v.y; cs.z += v.z; cs.w += v.w;
    }
    sHalf[h][c4] = cs;
  }
  __syncthreads();
  if (t < 128) {
    float4 a = sHalf[0][t], b2 = sHalf[1][t];
    float4 s;
    s.x = a.x + b2.x; s.y = a.y + b2.y; s.z = a.z + b2.z; s.w = a.w + b2.w;
    *(float4*)&sS[t * 4] = s;
  }
  __syncthreads();

  // |S|^2
  float p = sS[t] * sS[t] + sS[t + 256] * sS[t + 256];
  for (int off = 32; off; off >>= 1) p += __shfl_down(p, off);
  if ((t & 63) == 0) sred[t >> 6] = p;
  __syncthreads();
  if (t == 0) sS2v = sred[0] + sred[1] + sred[2] + sred[3];
  __syncthreads();
  const float S2 = sS2v;

  // per-utterance dot(e,S), |e|^2 from LDS (8 lanes per row)
  const int g = t >> 3, l = t & 7;
  float dotS = 0.f, e2 = 0.f;
  for (int i = 0; i < DIM / 8; ++i) {
    int d = i * 8 + l;
    float ev = sD[g * DIMP + d];
    dotS += ev * sS[d];
    e2 += ev * ev;
  }
  for (int off = 4; off; off >>= 1) {
    dotS += __shfl_down(dotS, off);
    e2 += __shfl_down(e2, off);
  }
  if (l == 0) {
    float numer = dotS - e2;                          // e.(S-e)
    float d2 = fmaxf(S2 - 2.f * dotS + e2, 1e-30f);   // |S-e|^2
    loo[j * MU + g] = numer / (sqrtf(e2) * sqrtf(d2));
    sInv[g] = 1.f / sqrtf(e2);
  }
  __syncthreads();

  // A blob: speaker j -> rb = j>>2; utterance m -> rp = (j&3)*2 + (m>>4).
  // 1024 16-B chunks: idx = (m 5b)(kt 2b)(kslot 2b)(half 1b)
  for (int i = 0; i < 4; ++i) {
    int idx = i * 256 + t;
    int m = idx >> 5;
    int c = idx & 31;
    int kt = c >> 3, kslot = (c >> 1) & 3, half = c & 1;
    float inv = sInv[m];
    const float* src = &sD[m * DIMP + kt * 128 + kslot * 32 + half * 16];
    int b0 = 0, b1 = 0, b2 = 0, b3 = 0;
    b0 = __builtin_amdgcn_cvt_pk_fp8_f32(src[0] * inv, src[1] * inv, b0, false);
    b0 = __builtin_amdgcn_cvt_pk_fp8_f32(src[2] * inv, src[3] * inv, b0, true);
    b1 = __builtin_amdgcn_cvt_pk_fp8_f32(src[4] * inv, src[5] * inv, b1, false);
    b1 = __builtin_amdgcn_cvt_pk_fp8_f32(src[6] * inv, src[7] * inv, b1, true);
    b2 = __builtin_amdgcn_cvt_pk_fp8_f32(src[8] * inv, src[9] * inv, b2, false);
    b2 = __builtin_amdgcn_cvt_pk_fp8_f32(src[10] * inv, src[11] * inv, b2, true);
    b3 = __builtin_amdgcn_cvt_pk_fp8_f32(src[12] * inv, src[13] * inv, b3, false);
    b3 = __builtin_amdgcn_cvt_pk_fp8_f32(src[14] * inv, src[15] * inv, b3, true);
    int rp = (j & 3) * 2 + (m >> 4);
    int lane2 = kslot * 16 + (m & 15);
    size_t byte = (((size_t)(j >> 2) * 4 + kt) << 14) + rp * 2048 +
                  half * 1024 + lane2 * 16;           // split half-planes
    *(int4*)(Af8 + byte) = make_int4(b0, b1, b2, b3);
  }

  // B blob: centroid j -> nb = j>>7, rp = (j>>4)&7, lanes kslot*16+(j&15).
  if (t < 32) {
    int c = t;
    int kt = c >> 3, kslot = (c >> 1) & 3, half = c & 1;
    float invc = 1.f / sqrtf(S2);
    const float* src = &sS[kt * 128 + kslot * 32 + half * 16];
    int b0 = 0, b1 = 0, b2 = 0, b3 = 0;
    b0 = __builtin_amdgcn_cvt_pk_fp8_f32(src[0] * invc, src[1] * invc, b0, false);
    b0 = __builtin_amdgcn_cvt_pk_fp8_f32(src[2] * invc, src[3] * invc, b0, true);
    b1 = __builtin_amdgcn_cvt_pk_fp8_f32(src[4] * invc, src[5] * invc, b1, false);
    b1 = __builtin_amdgcn_cvt_pk_fp8_f32(src[6] * invc, src[7] * invc, b1, true);
    b2 = __builtin_amdgcn_cvt_pk_fp8_f32(src[8] * invc, src[9] * invc, b2, false);
    b2 = __builtin_amdgcn_cvt_pk_fp8_f32(src[10] * invc, src[11] * invc, b2, true);
    b3 = __builtin_amdgcn_cvt_pk_fp8_f32(src[12] * invc, src[13] * invc, b3, false);
    b3 = __builtin_amdgcn_cvt_pk_fp8_f32(src[14] * invc, src[15] * invc, b3, true);
    int rp = (j >> 4) & 7;
    int lane2 = kslot * 16 + (j & 15);
    size_t byte = (((size_t)(j >> 7) * 4 + kt) << 14) + rp * 2048 +
                  half * 1024 + lane2 * 16;           // split half-planes
    *(int4*)(Bf8 + byte) = make_int4(b0, b1, b2, b3);
  }
}

// ---------------------------------------------------------------------------
// Kernel 2: MX-scaled fp8 K=128 MFMA GEMM (unit scales), 2-buffer pipeline.
// Tile 128x128, BK=128 -> 4 K-steps. 256 thr (4 waves, 2wm x 2wn), wave
// tile 64x64: acc[4][4] f32x4 = 64 AGPR + frag 64 + addr -> 2-3 waves/SIMD.
// R20 post-mortem: lane*32 fragment reads = 16-way bank conflict (2.1M
// counted). Fixed via split half-plane layout: both b128 reads per frag
// are lane*16 contiguous = conflict-free. All else identical to R20
// (which passed): mfma_scale_f32_16x16x128_f8f6f4, unit E8M0 scales,
// vmcnt(0)+barrier per round, STAGE(next) after barrier, lgkm(0)+16 MFMA.
// LDS 2x(16+16) KiB + 1 = 65 KiB -> 2 blocks/CU.
// Grid 2048 = 256 rb x 8 cb, XCD-chunked swizzle (32-rb band per XCD).
// ---------------------------------------------------------------------------
__global__ __launch_bounds__(256, 1) void k_gemm(
    const char* __restrict__ Af8,
    const char* __restrict__ Bf8,
    const float* __restrict__ wp,
    float* __restrict__ part,    // [8][NROW] partial sumexp per col-chunk
    float* __restrict__ diag)    // [NROW] raw cos vs own full centroid
{
  __shared__ char ldsA[2 * 16384];  // 32 KiB: 2 bufs x 16 KiB K-tile
  __shared__ char ldsB[2 * 16384];  // 32 KiB
  __shared__ float sPart[128][2];   // 1 KiB

  const int t = threadIdx.x;
  const int w = t >> 6, lane = t & 63;
  const int lr = lane & 15, lk = lane >> 4;
  const int wm = w >> 1, wn = w & 1;      // 2 x 2 wave grid
  // XCD-chunked block swizzle
  const int bid = blockIdx.x;
  const int xcd = bid & 7, ii = bid >> 3;     // ii in [0,256) per XCD
  const int rb = xcd * 32 + (ii >> 3);        // 0..255 (128 rows each)
  const int cb = ii & 7;                      // 0..7   (128 cols each)

  f32x4 acc[4][4];
#pragma unroll
  for (int a = 0; a < 4; ++a)
#pragma unroll
    for (int b = 0; b < 4; ++b) acc[a][b] = (f32x4)0.f;

  // staging: 16 KiB per tile per operand = 4 gload16/thread each
  const char* gA = Af8 + ((size_t)rb << 16) + t * 16;
  const char* gB = Bf8 + ((size_t)cb << 16) + t * 16;
  char* dA = &ldsA[t * 16];
  char* dB = &ldsB[t * 16];

#define STAGE(kt, bi)                                                        \
  {                                                                          \
    _Pragma("unroll")                                                        \
    for (int q = 0; q < 4; ++q) {                                            \
      GLOAD_LDS16(gA + ((size_t)(kt) << 14) + q * 4096,                      \
                  dA + ((bi) << 14) + q * 4096);                             \
      GLOAD_LDS16(gB + ((size_t)(kt) << 14) + q * 4096,                      \
                  dB + ((bi) << 14) + q * 4096);                             \
    }                                                                        \
  }

  // read bases: frag f at f*2048; lo half at +0, hi half at +1024;
  // lane addr = lane*16 (contiguous b128 = conflict-free)
  const char* lA0 = &ldsA[(wm * 4) * 2048 + lane * 16];
  const char* lB0 = &ldsB[(wn * 4) * 2048 + lane * 16];

  // ---- prologue ----
  STAGE(0, 0);

  // ---- K-loop: 4 rounds ----
#pragma unroll
  for (int kt = 0; kt < 4; ++kt) {
    asm volatile("s_waitcnt vmcnt(0)" ::: "memory");  // tile kt landed
    __builtin_amdgcn_s_barrier();
    __builtin_amdgcn_sched_barrier(0);

    if (kt < 3) STAGE(kt + 1, (kt + 1) & 1);

    // 16 ds_read_b128: 4 A-frags + 4 B-frags, split-half (conflict-free)
    i32x8 a8[4], b8[4];
#pragma unroll
    for (int f = 0; f < 4; ++f) {
      int4 lo = *(const int4*)(lA0 + ((kt & 1) << 14) + f * 2048);
      int4 hi = *(const int4*)(lA0 + ((kt & 1) << 14) + f * 2048 + 1024);
      a8[f][0] = lo.x; a8[f][1] = lo.y; a8[f][2] = lo.z; a8[f][3] = lo.w;
      a8[f][4] = hi.x; a8[f][5] = hi.y; a8[f][6] = hi.z; a8[f][7] = hi.w;
    }
#pragma unroll
    for (int f = 0; f < 4; ++f) {
      int4 lo = *(const int4*)(lB0 + ((kt & 1) << 14) + f * 2048);
      int4 hi = *(const int4*)(lB0 + ((kt & 1) << 14) + f * 2048 + 1024);
      b8[f][0] = lo.x; b8[f][1] = lo.y; b8[f][2] = lo.z; b8[f][3] = lo.w;
      b8[f][4] = hi.x; b8[f][5] = hi.y; b8[f][6] = hi.z; b8[f][7] = hi.w;
    }

    asm volatile("s_waitcnt lgkmcnt(0)" ::: "memory");
    __builtin_amdgcn_sched_barrier(0);

    __builtin_amdgcn_s_setprio(1);
#pragma unroll
    for (int mf = 0; mf < 4; ++mf)
#pragma unroll
      for (int nf = 0; nf < 4; ++nf)
        acc[mf][nf] = __builtin_amdgcn_mfma_scale_f32_16x16x128_f8f6f4(
            a8[mf], b8[nf], acc[mf][nf],
            0, 0,                       // cbsz=fp8(e4m3), blgp=fp8(e4m3)
            0, UNIT_SCALE,              // opselA, scaleA (x1.0)
            0, UNIT_SCALE);             // opselB, scaleB (x1.0)
    __builtin_amdgcn_s_setprio(0);
  }
#undef STAGE

  const float W = *wp;

  // ---- diag capture (raw cos) before exp consumes acc ----
  // block rows = speakers rb*4..+3; col c = rb*4+sp in this block iff
  // cb == c>>7 (= rb>>5, no carry since sp<4).
  if (cb == (rb >> 5)) {
#pragma unroll
    for (int sp = 0; sp < 4; ++sp) {
      const int c = rb * 4 + sp;
      if (wm == (sp >> 1) && wn == ((c >> 6) & 1)) {
        const int nfo = (c >> 4) & 3;
#pragma unroll
        for (int mh = 0; mh < 2; ++mh) {
          f32x4 dsel = acc[(sp & 1) * 2 + mh][0];
#pragma unroll
          for (int nf = 1; nf < 4; ++nf)
            if (nf == nfo) dsel = acc[(sp & 1) * 2 + mh][nf];  // static idx
          if (lr == (c & 15)) {
#pragma unroll
            for (int i = 0; i < 4; ++i)
              diag[c * 32 + mh * 16 + lk * 4 + i] = dsel[i];
          }
        }
      }
    }
  }

  // ---- fused epilogue: exp((fmax(cos,eps)-1)*W), reduce over 64 cols ----
#pragma unroll
  for (int mf = 0; mf < 4; ++mf)
#pragma unroll
    for (int i = 0; i < 4; ++i) {
      float s = 0.f;
#pragma unroll
      for (int nf = 0; nf < 4; ++nf)
        s += __expf((fmaxf(acc[mf][nf][i], EPS) - 1.f) * W);
      s += __shfl_xor(s, 1);
      s += __shfl_xor(s, 2);
      s += __shfl_xor(s, 4);
      s += __shfl_xor(s, 8);
      if (lr == 0) sPart[wm * 64 + mf * 16 + lk * 4 + i][wn] = s;
    }
  __syncthreads();
  if (t < 128)
    part[(size_t)cb * NROW + rb * 128 + t] = sPart[t][0] + sPart[t][1];
}

// ---------------------------------------------------------------------------
// Final: sum 8 col-chunk partials, swap exp(diag)->exp(loo), close lse,
// deterministic 2-stage sum.  L_row = log(s - exp(dt) + exp(lt)) - lt
// ---------------------------------------------------------------------------
__global__ __launch_bounds__(256) void k_final1(
    const float* __restrict__ part, const float* __restrict__ loo,
    const float* __restrict__ diag, const float* __restrict__ wp,
    float* __restrict__ p2)
{
  const int t = threadIdx.x;
  const int r = blockIdx.x * 256 + t;
  const float W = *wp;
  float s = 0.f;
#pragma unroll
  for (int c = 0; c < 8; ++c) s += part[(size_t)c * NROW + r];
  const float lt = (fmaxf(loo[r], EPS) - 1.f) * W;
  const float dt = (fmaxf(diag[r], EPS) - 1.f) * W;
  s += __expf(lt) - __expf(dt);
  float v = logf(s) - lt;
  __shared__ float red[4];
  for (int off = 32; off; off >>= 1) v += __shfl_down(v, off);
  if ((t & 63) == 0) red[t >> 6] = v;
  __syncthreads();
  if (t == 0) p2[blockIdx.x] = red[0] + red[1] + red[2] + red[3];
}

__global__ __launch_bounds__(128) void k_final2(
    const float* __restrict__ p2, float* __restrict__ out)
{
  const int t = threadIdx.x;
  float v = p2[t];
  for (int off = 32; off; off >>= 1) v += __shfl_down(v, off);
  __shared__ float red[2];
  if ((t & 63) == 0) red[t >> 6] = v;
  __syncthreads();
  if (t == 0) out[0] = red[0] + red[1];
}

extern "C" void kernel_launch(void* const* d_in, const int* in_sizes, int n_in,
                              void* d_out, int out_size, void* d_ws, size_t ws_size,
                              hipStream_t stream) {
  const float* dvecs = (const float*)d_in[0];
  const float* wptr  = (const float*)d_in[1];
  // b cancels algebraically (shift = w+b subtracted and re-added) -> unused
  float* out = (float*)d_out;

  char* ws = (char*)d_ws;
  char* Af8 = ws;            ws += (size_t)NROW * DIM;          // 16 MiB
  char* Bf8 = ws;            ws += (size_t)NSPK * DIM;          // 512 KiB
  float* loo  = (float*)ws;  ws += (size_t)NROW * sizeof(float);
  float* diag = (float*)ws;  ws += (size_t)NROW * sizeof(float);
  float* part = (float*)ws;  ws += (size_t)8 * NROW * sizeof(float);  // 1 MiB
  float* p2   = (float*)ws;

  k_prep<<<NSPK, 256, 0, stream>>>(dvecs, Af8, Bf8, loo);
  k_gemm<<<2048, 256, 0, stream>>>(Af8, Bf8, wptr, part, diag);
  k_final1<<<NROW / 256, 256, 0, stream>>>(part, loo, diag, wptr, p2);
  k_final2<<<1, 128, 0, stream>>>(p2, out);
}